// Round 1
// baseline (912.743 us; speedup 1.0000x reference)
//
#include <hip/hip_runtime.h>
#include <cstdint>
#include <cstddef>

// Problem constants
#define NHEAD 9
#define CHN   256
#define NB    8
#define WH    48
#define SS    2304            // 48*48
#define NBD   2048            // NB*CHN
#define OUT0  4718592         // 8*256*48*48
// probs region: 47,775,744 floats after OUT0

__device__ __forceinline__ float bf2f(unsigned int u16) {
    union { unsigned int i; float f; } v; v.i = u16 << 16; return v.f;
}
__device__ __forceinline__ unsigned short f2bf(float f) {
    union { float f; unsigned int i; } v; v.f = f;
    unsigned int x = v.i;
    unsigned int r = x + 0x7fffu + ((x >> 16) & 1u);   // RNE
    return (unsigned short)(r >> 16);
}

// ---------------------------------------------------------------------------
// K1: 1D softmaxes. p1[h][i][k], p2[h][j][l] + transposes p1t[k][h][i], p2t[l][h][j]
// grid: 432 blocks (h*48+r), 64 threads
// ---------------------------------------------------------------------------
__global__ __launch_bounds__(64) void k_pinit(const float* __restrict__ centers,
                                              const float* __restrict__ spreads,
                                              float* __restrict__ p1, float* __restrict__ p2,
                                              float* __restrict__ p1t, float* __restrict__ p2t) {
    int blk = blockIdx.x;
    int h = blk / 48, r = blk % 48;
    int lane = threadIdx.x;
    float a = spreads[h]; a = a * a;
    float mu1 = centers[2 * h + 0];
    float mu2 = centers[2 * h + 1];
    bool act = lane < 48;
    float dx = (float)(lane - r);
    float q  = -0.5f * a * dx * dx;
    float g1 = act ? (a * mu1 * dx + q) : -INFINITY;
    float g2 = act ? (a * mu2 * dx + q) : -INFINITY;
    float m1 = g1, m2 = g2;
    #pragma unroll
    for (int off = 32; off >= 1; off >>= 1) {
        m1 = fmaxf(m1, __shfl_xor(m1, off));
        m2 = fmaxf(m2, __shfl_xor(m2, off));
    }
    float e1 = act ? expf(g1 - m1) : 0.f;
    float e2 = act ? expf(g2 - m2) : 0.f;
    float s1 = e1, s2 = e2;
    #pragma unroll
    for (int off = 32; off >= 1; off >>= 1) {
        s1 += __shfl_xor(s1, off);
        s2 += __shfl_xor(s2, off);
    }
    if (act) {
        float v1 = e1 / s1, v2 = e2 / s2;
        p1 [h * SS + r * 48 + lane] = v1;
        p2 [h * SS + r * 48 + lane] = v2;
        p1t[lane * 432 + h * 48 + r] = v1;
        p2t[lane * 432 + h * 48 + r] = v2;
    }
}

// ---------------------------------------------------------------------------
// K2: probs[i][j][h][k][l] = p1[h][i][k]*p2[h][j][l].  Runs LAST (overwrites scratch).
// grid: 20736 blocks = (i*48+j)*9+h, 256 threads, float4 stores
// ---------------------------------------------------------------------------
__global__ __launch_bounds__(256) void k_probs(const float* __restrict__ p1,
                                               const float* __restrict__ p2,
                                               float* __restrict__ probs) {
    int blk = blockIdx.x;
    int h = blk % 9; int ij = blk / 9; int j = ij % 48; int i = ij / 48;
    __shared__ float p1row[48];
    __shared__ float4 p2row[12];
    int t = threadIdx.x;
    if (t < 48) p1row[t] = p1[(h * 48 + i) * 48 + t];
    else if (t < 60) p2row[t - 48] = ((const float4*)(p2 + (h * 48 + j) * 48))[t - 48];
    __syncthreads();
    float4* op = (float4*)(probs + (size_t)blk * SS);
    #pragma unroll
    for (int idx = t; idx < 576; idx += 256) {
        int e4 = idx * 4;
        int k = e4 / 48, l = e4 % 48;
        float s = p1row[k];
        float4 qv = p2row[l >> 2];
        float4 v; v.x = s * qv.x; v.y = s * qv.y; v.z = s * qv.z; v.w = s * qv.w;
        op[idx] = v;
    }
}

// ---------------------------------------------------------------------------
// K3 (GEMM-A): S(h,i,bd,l) = sum_k p1[h,i,k]*hs[bd,l,k]
// per block: h, bd-pair.  C tile 48(m=i) x 96(n=bd'*48+l), K=48.  bf16 out
// S2 layout [h][l][bd][i]  (K-major for GEMM-B)
// grid: 9216 = h*1024+nb, 128 threads, thread tile 6x6
// ---------------------------------------------------------------------------
__global__ __launch_bounds__(128) void k_gemmA(const float* __restrict__ hs,
                                               const float* __restrict__ p1t,
                                               unsigned short* __restrict__ S2) {
    int h = blockIdx.x >> 10;
    int nb = blockIdx.x & 1023;
    int bd0 = nb * 2;
    __shared__ float lds[48 * 52 + 48 * 100];
    float* At = lds;               // [k][52] : p1t slice, m=i
    float* Bt = lds + 48 * 52;     // [k][100]: transposed hs
    int t = threadIdx.x;
    for (int o = t; o < 2304; o += 128) {
        int k = o / 48, i = o % 48;
        At[k * 52 + i] = p1t[k * 432 + h * 48 + i];
    }
    for (int o = t; o < 4608; o += 128) {
        int bdp = o / 2304; int rr = o - bdp * 2304; int l = rr / 48, k = rr % 48;
        Bt[k * 100 + bdp * 48 + l] = hs[(size_t)(bd0 + bdp) * SS + l * 48 + k];
    }
    __syncthreads();
    int m0 = (t >> 4) * 6, n0 = (t & 15) * 6;
    float acc[6][6];
    #pragma unroll
    for (int a = 0; a < 6; a++)
        #pragma unroll
        for (int bq = 0; bq < 6; bq++) acc[a][bq] = 0.f;
    for (int k = 0; k < 48; ++k) {
        float av[6], bv[6];
        const float* Ar = &At[k * 52 + m0];
        const float* Br = &Bt[k * 100 + n0];
        *(float2*)&av[0] = *(const float2*)&Ar[0];
        *(float2*)&av[2] = *(const float2*)&Ar[2];
        *(float2*)&av[4] = *(const float2*)&Ar[4];
        *(float2*)&bv[0] = *(const float2*)&Br[0];
        *(float2*)&bv[2] = *(const float2*)&Br[2];
        *(float2*)&bv[4] = *(const float2*)&Br[4];
        #pragma unroll
        for (int mm = 0; mm < 6; ++mm)
            #pragma unroll
            for (int nn = 0; nn < 6; ++nn)
                acc[mm][nn] += av[mm] * bv[nn];
    }
    __syncthreads();
    float* Cls = lds;  // [n'][m] = [96][48]
    #pragma unroll
    for (int nn = 0; nn < 6; ++nn)
        #pragma unroll
        for (int mm = 0; mm < 6; ++mm)
            Cls[(n0 + nn) * 48 + (m0 + mm)] = acc[mm][nn];
    __syncthreads();
    size_t hb = (size_t)h * 48 * 98304;
    for (int o = t; o < 4608; o += 128) {
        int np = o / 48, i = o % 48;
        int bdp = np / 48, l = np % 48;
        S2[hb + (size_t)l * 98304 + (size_t)(bd0 + bdp) * 48 + i] = f2bf(Cls[o]);
    }
}

// ---------------------------------------------------------------------------
// K4 (GEMM-B): vals(b,i,j,h,d) = sum_l p2[h,j,l]*S(h,i,bd,l)
// C tile 48(m=j) x 96(n=bd'*48+i), K=48(l).  vals layout [b][h*256+d][j*48+i]
// grid: 9216 = h*1024+nb, 128 threads
// ---------------------------------------------------------------------------
__global__ __launch_bounds__(128) void k_gemmB(const unsigned short* __restrict__ S2,
                                               const float* __restrict__ p2t,
                                               unsigned short* __restrict__ valsw) {
    int h = blockIdx.x >> 10;
    int nb = blockIdx.x & 1023;
    __shared__ float lds[48 * 52 + 48 * 100];
    float* At = lds;
    float* Bt = lds + 48 * 52;
    int t = threadIdx.x;
    for (int o = t; o < 2304; o += 128) {
        int l = o / 48, j = o % 48;
        At[l * 52 + j] = p2t[l * 432 + h * 48 + j];
    }
    const unsigned int* S2u = (const unsigned int*)S2;
    for (int o = t; o < 2304; o += 128) {
        int l = o / 48, c2 = o % 48;
        unsigned int u = S2u[(size_t)h * 2359296 + (size_t)l * 49152 + nb * 48 + c2];
        Bt[l * 100 + 2 * c2]     = bf2f(u & 0xffffu);
        Bt[l * 100 + 2 * c2 + 1] = bf2f(u >> 16);
    }
    __syncthreads();
    int m0 = (t >> 4) * 6, n0 = (t & 15) * 6;
    float acc[6][6];
    #pragma unroll
    for (int a = 0; a < 6; a++)
        #pragma unroll
        for (int bq = 0; bq < 6; bq++) acc[a][bq] = 0.f;
    for (int k = 0; k < 48; ++k) {
        float av[6], bv[6];
        const float* Ar = &At[k * 52 + m0];
        const float* Br = &Bt[k * 100 + n0];
        *(float2*)&av[0] = *(const float2*)&Ar[0];
        *(float2*)&av[2] = *(const float2*)&Ar[2];
        *(float2*)&av[4] = *(const float2*)&Ar[4];
        *(float2*)&bv[0] = *(const float2*)&Br[0];
        *(float2*)&bv[2] = *(const float2*)&Br[2];
        *(float2*)&bv[4] = *(const float2*)&Br[4];
        #pragma unroll
        for (int mm = 0; mm < 6; ++mm)
            #pragma unroll
            for (int nn = 0; nn < 6; ++nn)
                acc[mm][nn] += av[mm] * bv[nn];
    }
    __syncthreads();
    float* Cls = lds;  // [m=j][n'=c] = [48][96]
    #pragma unroll
    for (int nn = 0; nn < 6; ++nn)
        #pragma unroll
        for (int mm = 0; mm < 6; ++mm)
            Cls[(m0 + mm) * 96 + (n0 + nn)] = acc[mm][nn];
    __syncthreads();
    for (int o = t; o < 4608; o += 128) {
        int j = o / 96, c = o % 96;
        int bdp = c / 48, i = c % 48;
        int bd = nb * 2 + bdp;
        int b = bd >> 8, d = bd & 255;
        valsw[(size_t)((b * 9 + h) * 256 + d) * SS + j * 48 + i] = f2bf(Cls[o]);
    }
}

// ---------------------------------------------------------------------------
// K5 (GEMM-C): out[b][e][m] = sum_k vals[b][k][m]*Wv[e][k] + vb[e]   (m=j*48+i)
// per b: M=2304, N=256, K=2304.  Block tile 96x64, k-chunk 32, thread 6x4.
// grid: 768 = b*96 + mb*4 + nb, 256 threads
// ---------------------------------------------------------------------------
__global__ __launch_bounds__(256) void k_gemmC(const unsigned short* __restrict__ valsw,
                                               const float* __restrict__ Wv,
                                               const float* __restrict__ vb,
                                               float* __restrict__ out) {
    int blk = blockIdx.x;
    int b = blk / 96; int r = blk % 96; int mb = r >> 2; int nb = r & 3;
    __shared__ float Al[32 * 100];
    __shared__ float Wl[32 * 68];
    int t = threadIdx.x;
    int tx = t & 15, ty = t >> 4;
    int m0 = tx * 6, e0 = ty * 4;
    int m0g = mb * 96, e0g = nb * 64;
    float acc[6][4];
    #pragma unroll
    for (int a = 0; a < 6; a++)
        #pragma unroll
        for (int c = 0; c < 4; c++) acc[a][c] = 0.f;
    const unsigned int* Au = (const unsigned int*)(valsw + (size_t)b * 5308416);
    for (int kb = 0; kb < 72; ++kb) {
        int k0 = kb * 32;
        for (int o = t; o < 1536; o += 256) {
            int k = o / 48, mp = o % 48;
            unsigned int u = Au[(size_t)(k0 + k) * 1152 + (m0g >> 1) + mp];
            Al[k * 100 + 2 * mp]     = bf2f(u & 0xffffu);
            Al[k * 100 + 2 * mp + 1] = bf2f(u >> 16);
        }
        for (int o = t; o < 2048; o += 256) {
            int e = o >> 5, k = o & 31;
            Wl[k * 68 + e] = Wv[(size_t)(e0g + e) * SS + k0 + k];
        }
        __syncthreads();
        #pragma unroll 8
        for (int k = 0; k < 32; ++k) {
            float av[6], wvr[4];
            const float* Ar = &Al[k * 100 + m0];
            *(float2*)&av[0] = *(const float2*)&Ar[0];
            *(float2*)&av[2] = *(const float2*)&Ar[2];
            *(float2*)&av[4] = *(const float2*)&Ar[4];
            *(float4*)&wvr[0] = *(const float4*)&Wl[k * 68 + e0];
            #pragma unroll
            for (int mm = 0; mm < 6; ++mm)
                #pragma unroll
                for (int ee = 0; ee < 4; ++ee)
                    acc[mm][ee] += av[mm] * wvr[ee];
        }
        __syncthreads();
    }
    size_t obase = (size_t)b * 589824;
    #pragma unroll
    for (int ee = 0; ee < 4; ++ee) {
        int e = e0g + e0 + ee;
        float bias = vb[e];
        float* op = out + obase + (size_t)e * SS + m0g + m0;
        #pragma unroll
        for (int mm = 0; mm < 6; ++mm) op[mm] = acc[mm][ee] + bias;
    }
}

// ---------------------------------------------------------------------------
extern "C" void kernel_launch(void* const* d_in, const int* in_sizes, int n_in,
                              void* d_out, int out_size, void* d_ws, size_t ws_size,
                              hipStream_t stream) {
    const float* hs      = (const float*)d_in[0];
    const float* centers = (const float*)d_in[1];
    const float* spreads = (const float*)d_in[2];
    const float* Wv      = (const float*)d_in[3];
    const float* vbias   = (const float*)d_in[4];

    float* out   = (float*)d_out;
    float* probs = out + OUT0;                   // 47,775,744 floats

    float* p1  = (float*)d_ws;                   // 20736 floats each
    float* p2  = p1 + 20736;
    float* p1t = p2 + 20736;
    float* p2t = p1t + 20736;

    // Scratch lives inside the probs output region (191 MB >= 170 MB needed);
    // k_probs runs last and overwrites it.
    unsigned short* S2   = (unsigned short*)probs;      // 42,467,328 bf16
    unsigned short* vals = S2 + 42467328;               // 42,467,328 bf16

    k_pinit<<<432, 64, 0, stream>>>(centers, spreads, p1, p2, p1t, p2t);
    k_gemmA<<<9216, 128, 0, stream>>>(hs, p1t, S2);
    k_gemmB<<<9216, 128, 0, stream>>>(S2, p2t, vals);
    k_gemmC<<<768, 256, 0, stream>>>(vals, Wv, vbias, out);
    k_probs<<<20736, 256, 0, stream>>>(p1, p2, probs);
}

// Round 2
// 519.109 us; speedup vs baseline: 1.7583x; 1.7583x over previous
//
#include <hip/hip_runtime.h>
#include <cstdint>
#include <cstddef>

// Problem constants
#define NHEAD 9
#define CHN   256
#define NB    8
#define WH    48
#define SS    2304            // 48*48
#define OUT0  4718592         // 8*256*48*48
// probs region: 47,775,744 floats after OUT0

typedef short bf16x8 __attribute__((ext_vector_type(8)));
typedef float f32x4  __attribute__((ext_vector_type(4)));

__device__ __forceinline__ float bf2f(unsigned int u16) {
    union { unsigned int i; float f; } v; v.i = u16 << 16; return v.f;
}
__device__ __forceinline__ unsigned short f2bf(float f) {
    union { float f; unsigned int i; } v; v.f = f;
    unsigned int x = v.i;
    unsigned int r = x + 0x7fffu + ((x >> 16) & 1u);   // RNE
    return (unsigned short)(r >> 16);
}

// ---------------------------------------------------------------------------
// K1: 1D softmaxes. p1[h][i][k], p2[h][j][l] + transposes p1t[k][h][i], p2t[l][h][j]
// ---------------------------------------------------------------------------
__global__ __launch_bounds__(64) void k_pinit(const float* __restrict__ centers,
                                              const float* __restrict__ spreads,
                                              float* __restrict__ p1, float* __restrict__ p2,
                                              float* __restrict__ p1t, float* __restrict__ p2t) {
    int blk = blockIdx.x;
    int h = blk / 48, r = blk % 48;
    int lane = threadIdx.x;
    float a = spreads[h]; a = a * a;
    float mu1 = centers[2 * h + 0];
    float mu2 = centers[2 * h + 1];
    bool act = lane < 48;
    float dx = (float)(lane - r);
    float q  = -0.5f * a * dx * dx;
    float g1 = act ? (a * mu1 * dx + q) : -INFINITY;
    float g2 = act ? (a * mu2 * dx + q) : -INFINITY;
    float m1 = g1, m2 = g2;
    #pragma unroll
    for (int off = 32; off >= 1; off >>= 1) {
        m1 = fmaxf(m1, __shfl_xor(m1, off));
        m2 = fmaxf(m2, __shfl_xor(m2, off));
    }
    float e1 = act ? expf(g1 - m1) : 0.f;
    float e2 = act ? expf(g2 - m2) : 0.f;
    float s1 = e1, s2 = e2;
    #pragma unroll
    for (int off = 32; off >= 1; off >>= 1) {
        s1 += __shfl_xor(s1, off);
        s2 += __shfl_xor(s2, off);
    }
    if (act) {
        float v1 = e1 / s1, v2 = e2 / s2;
        p1 [h * SS + r * 48 + lane] = v1;
        p2 [h * SS + r * 48 + lane] = v2;
        p1t[lane * 432 + h * 48 + r] = v1;
        p2t[lane * 432 + h * 48 + r] = v2;
    }
}

// ---------------------------------------------------------------------------
// K2: probs[i][j][h][k][l] = p1[h][i][k]*p2[h][j][l].  Runs LAST (overwrites scratch).
// ---------------------------------------------------------------------------
__global__ __launch_bounds__(256) void k_probs(const float* __restrict__ p1,
                                               const float* __restrict__ p2,
                                               float* __restrict__ probs) {
    int blk = blockIdx.x;
    int h = blk % 9; int ij = blk / 9; int j = ij % 48; int i = ij / 48;
    __shared__ float p1row[48];
    __shared__ float4 p2row[12];
    int t = threadIdx.x;
    if (t < 48) p1row[t] = p1[(h * 48 + i) * 48 + t];
    else if (t < 60) p2row[t - 48] = ((const float4*)(p2 + (h * 48 + j) * 48))[t - 48];
    __syncthreads();
    float4* op = (float4*)(probs + (size_t)blk * SS);
    for (int idx = t; idx < 576; idx += 256) {
        int e4 = idx * 4;
        int k = e4 / 48, l = e4 % 48;
        float s = p1row[k];
        float4 qv = p2row[l >> 2];
        float4 v; v.x = s * qv.x; v.y = s * qv.y; v.z = s * qv.z; v.w = s * qv.w;
        op[idx] = v;
    }
}

// ---------------------------------------------------------------------------
// K3 (GEMM-A): S(h,i,bd,l) = sum_k p1[h,i,k]*hs[bd,l,k]
// S2 layout [h][l][bd][i]  (K-major for GEMM-B)
// ---------------------------------------------------------------------------
__global__ __launch_bounds__(128) void k_gemmA(const float* __restrict__ hs,
                                               const float* __restrict__ p1t,
                                               unsigned short* __restrict__ S2) {
    int h = blockIdx.x >> 10;
    int nb = blockIdx.x & 1023;
    int bd0 = nb * 2;
    __shared__ float lds[48 * 52 + 48 * 100];
    float* At = lds;               // [k][52] : p1t slice, m=i
    float* Bt = lds + 48 * 52;     // [k][100]: transposed hs
    int t = threadIdx.x;
    for (int o = t; o < 2304; o += 128) {
        int k = o / 48, i = o % 48;
        At[k * 52 + i] = p1t[k * 432 + h * 48 + i];
    }
    for (int o = t; o < 4608; o += 128) {
        int bdp = o / 2304; int rr = o - bdp * 2304; int l = rr / 48, k = rr % 48;
        Bt[k * 100 + bdp * 48 + l] = hs[(size_t)(bd0 + bdp) * SS + l * 48 + k];
    }
    __syncthreads();
    int m0 = (t >> 4) * 6, n0 = (t & 15) * 6;
    float acc[6][6];
    #pragma unroll
    for (int a = 0; a < 6; a++)
        #pragma unroll
        for (int bq = 0; bq < 6; bq++) acc[a][bq] = 0.f;
    for (int k = 0; k < 48; ++k) {
        float av[6], bv[6];
        const float* Ar = &At[k * 52 + m0];
        const float* Br = &Bt[k * 100 + n0];
        *(float2*)&av[0] = *(const float2*)&Ar[0];
        *(float2*)&av[2] = *(const float2*)&Ar[2];
        *(float2*)&av[4] = *(const float2*)&Ar[4];
        *(float2*)&bv[0] = *(const float2*)&Br[0];
        *(float2*)&bv[2] = *(const float2*)&Br[2];
        *(float2*)&bv[4] = *(const float2*)&Br[4];
        #pragma unroll
        for (int mm = 0; mm < 6; ++mm)
            #pragma unroll
            for (int nn = 0; nn < 6; ++nn)
                acc[mm][nn] += av[mm] * bv[nn];
    }
    __syncthreads();
    float* Cls = lds;  // [n'][m] = [96][48]
    #pragma unroll
    for (int nn = 0; nn < 6; ++nn)
        #pragma unroll
        for (int mm = 0; mm < 6; ++mm)
            Cls[(n0 + nn) * 48 + (m0 + mm)] = acc[mm][nn];
    __syncthreads();
    size_t hb = (size_t)h * 48 * 98304;
    for (int o = t; o < 4608; o += 128) {
        int np = o / 48, i = o % 48;
        int bdp = np / 48, l = np % 48;
        S2[hb + (size_t)l * 98304 + (size_t)(bd0 + bdp) * 48 + i] = f2bf(Cls[o]);
    }
}

// ---------------------------------------------------------------------------
// K4 (GEMM-B): vals(b,i,j,h,d) = sum_l p2[h,j,l]*S(h,i,bd,l)
// Output: AF[b][kb][m][kk]  (MFMA A-fragment-ready; kb=k>>3, kk=k&7, k=h*256+d, m=j*48+i)
// ---------------------------------------------------------------------------
__global__ __launch_bounds__(128) void k_gemmB(const unsigned short* __restrict__ S2,
                                               const float* __restrict__ p2t,
                                               unsigned int* __restrict__ AFu) {
    int h = blockIdx.x >> 10;
    int nb = blockIdx.x & 1023;
    __shared__ float lds[48 * 52 + 48 * 100];
    float* At = lds;
    float* Bt = lds + 48 * 52;
    int t = threadIdx.x;
    for (int o = t; o < 2304; o += 128) {
        int l = o / 48, j = o % 48;
        At[l * 52 + j] = p2t[l * 432 + h * 48 + j];
    }
    const unsigned int* S2u = (const unsigned int*)S2;
    for (int o = t; o < 2304; o += 128) {
        int l = o / 48, c2 = o % 48;
        unsigned int u = S2u[(size_t)h * 2359296 + (size_t)l * 49152 + nb * 48 + c2];
        Bt[l * 100 + 2 * c2]     = bf2f(u & 0xffffu);
        Bt[l * 100 + 2 * c2 + 1] = bf2f(u >> 16);
    }
    __syncthreads();
    int m0 = (t >> 4) * 6, n0 = (t & 15) * 6;
    float acc[6][6];
    #pragma unroll
    for (int a = 0; a < 6; a++)
        #pragma unroll
        for (int bq = 0; bq < 6; bq++) acc[a][bq] = 0.f;
    for (int k = 0; k < 48; ++k) {
        float av[6], bv[6];
        const float* Ar = &At[k * 52 + m0];
        const float* Br = &Bt[k * 100 + n0];
        *(float2*)&av[0] = *(const float2*)&Ar[0];
        *(float2*)&av[2] = *(const float2*)&Ar[2];
        *(float2*)&av[4] = *(const float2*)&Ar[4];
        *(float2*)&bv[0] = *(const float2*)&Br[0];
        *(float2*)&bv[2] = *(const float2*)&Br[2];
        *(float2*)&bv[4] = *(const float2*)&Br[4];
        #pragma unroll
        for (int mm = 0; mm < 6; ++mm)
            #pragma unroll
            for (int nn = 0; nn < 6; ++nn)
                acc[mm][nn] += av[mm] * bv[nn];
    }
    __syncthreads();
    float* Cls = lds;  // [m=j][n'=c] = [48][96], c = bdp*48+i
    #pragma unroll
    for (int nn = 0; nn < 6; ++nn)
        #pragma unroll
        for (int mm = 0; mm < 6; ++mm)
            Cls[(m0 + mm) * 96 + (n0 + nn)] = acc[mm][nn];
    __syncthreads();
    // Epilogue: pack pair (d0, d0+1) into one dword, frag-ready layout
    int bd0 = nb * 2;
    int b = bd0 >> 8, d0 = bd0 & 255;
    int kb = h * 32 + (d0 >> 3);
    int sh = (d0 & 7) >> 1;                 // dword slot within the 16B kk-group
    size_t base = ((size_t)(b * 288 + kb) * 2304) * 4 + sh;   // in u32 units
    for (int o = t; o < 2304; o += 128) {
        int j = o / 48, i = o % 48;         // m = j*48+i = o
        float v0 = Cls[j * 96 + i];
        float v1 = Cls[j * 96 + 48 + i];
        unsigned int u = (unsigned int)f2bf(v0) | ((unsigned int)f2bf(v1) << 16);
        AFu[base + (size_t)o * 4] = u;
    }
}

// ---------------------------------------------------------------------------
// K5: pack Wv (fp32 [e][k]) -> WF bf16 [kb][e][kk]  (MFMA B-fragment-ready)
// grid 288 blocks x 256 threads
// ---------------------------------------------------------------------------
__global__ __launch_bounds__(256) void k_wpack(const float* __restrict__ Wv,
                                               unsigned short* __restrict__ WF) {
    int kb = blockIdx.x;       // 0..287
    int e  = threadIdx.x;      // 0..255
    const float* src = Wv + (size_t)e * 2304 + kb * 8;
    float4 f0 = *(const float4*)src;
    float4 f1 = *(const float4*)(src + 4);
    uint4 o;
    o.x = (unsigned int)f2bf(f0.x) | ((unsigned int)f2bf(f0.y) << 16);
    o.y = (unsigned int)f2bf(f0.z) | ((unsigned int)f2bf(f0.w) << 16);
    o.z = (unsigned int)f2bf(f1.x) | ((unsigned int)f2bf(f1.y) << 16);
    o.w = (unsigned int)f2bf(f1.z) | ((unsigned int)f2bf(f1.w) << 16);
    *(uint4*)(WF + ((size_t)kb * 256 + e) * 8) = o;
}

// ---------------------------------------------------------------------------
// K6 (GEMM-C, MFMA): out[b][e][m] = sum_k AF(k,m)*W(e,k) + vb[e]
// Per batch: M=2304(m), N=256(e), K=2304.  BM=64, BN=128, 256 thr = 4 waves.
// Wave tile 32m x 64e = 2x4 MFMA tiles of 16x16, BK=32/iter, no LDS, no barriers.
// grid: 576 = b*72 + mb*2 + nbk
// ---------------------------------------------------------------------------
__global__ __launch_bounds__(256) void k_gemmC(const unsigned short* __restrict__ AF,
                                               const unsigned short* __restrict__ WF,
                                               const float* __restrict__ vb,
                                               float* __restrict__ out) {
    int blk = blockIdx.x;
    int b = blk / 72; int r = blk % 72; int mb = r >> 1; int nbk = r & 1;
    int t = threadIdx.x;
    int lane = t & 63, wave = t >> 6;
    int l15 = lane & 15, quad = lane >> 4;
    int wm = wave & 1, we = wave >> 1;
    int m0 = mb * 64 + wm * 32;
    int e0 = nbk * 128 + we * 64;

    const bf16x8* pa = (const bf16x8*)AF + (size_t)b * 288 * 2304
                       + (size_t)quad * 2304 + m0 + l15;      // +tm*16; chunk step 9216
    const bf16x8* pw = (const bf16x8*)WF + (size_t)quad * 256 + e0 + l15;  // +te*16; chunk step 1024

    f32x4 acc[2][4];
    #pragma unroll
    for (int i = 0; i < 2; i++)
        #pragma unroll
        for (int j = 0; j < 4; j++) acc[i][j] = (f32x4){0.f, 0.f, 0.f, 0.f};

    bf16x8 a_cur[2], w_cur[4], a_nxt[2], w_nxt[4];
    a_cur[0] = pa[0];  a_cur[1] = pa[16];
    w_cur[0] = pw[0];  w_cur[1] = pw[16]; w_cur[2] = pw[32]; w_cur[3] = pw[48];

    for (int c = 0; c < 72; ++c) {
        if (c < 71) {
            a_nxt[0] = pa[9216];      a_nxt[1] = pa[9216 + 16];
            w_nxt[0] = pw[1024];      w_nxt[1] = pw[1024 + 16];
            w_nxt[2] = pw[1024 + 32]; w_nxt[3] = pw[1024 + 48];
        }
        #pragma unroll
        for (int tm = 0; tm < 2; ++tm)
            #pragma unroll
            for (int te = 0; te < 4; ++te)
                acc[tm][te] = __builtin_amdgcn_mfma_f32_16x16x32_bf16(
                    a_cur[tm], w_cur[te], acc[tm][te], 0, 0, 0);
        a_cur[0] = a_nxt[0]; a_cur[1] = a_nxt[1];
        w_cur[0] = w_nxt[0]; w_cur[1] = w_nxt[1]; w_cur[2] = w_nxt[2]; w_cur[3] = w_nxt[3];
        pa += 9216; pw += 1024;
    }

    size_t obase = (size_t)b * 589824;
    #pragma unroll
    for (int te = 0; te < 4; ++te) {
        int e = e0 + te * 16 + l15;
        float bias = vb[e];
        #pragma unroll
        for (int tm = 0; tm < 2; ++tm) {
            int m = m0 + tm * 16 + quad * 4;
            float4 v;
            v.x = acc[tm][te][0] + bias;
            v.y = acc[tm][te][1] + bias;
            v.z = acc[tm][te][2] + bias;
            v.w = acc[tm][te][3] + bias;
            *(float4*)(out + obase + (size_t)e * 2304 + m) = v;
        }
    }
}

// ---------------------------------------------------------------------------
extern "C" void kernel_launch(void* const* d_in, const int* in_sizes, int n_in,
                              void* d_out, int out_size, void* d_ws, size_t ws_size,
                              hipStream_t stream) {
    const float* hs      = (const float*)d_in[0];
    const float* centers = (const float*)d_in[1];
    const float* spreads = (const float*)d_in[2];
    const float* Wv      = (const float*)d_in[3];
    const float* vbias   = (const float*)d_in[4];

    float* out   = (float*)d_out;
    float* probs = out + OUT0;                   // 47,775,744 floats (191 MB)

    float* p1  = (float*)d_ws;                   // 20736 floats each
    float* p2  = p1 + 20736;
    float* p1t = p2 + 20736;
    float* p2t = p1t + 20736;

    // Scratch inside the probs output region; k_probs runs last and overwrites.
    unsigned short* S2 = (unsigned short*)probs;        // 42,467,328 bf16 (84.9 MB)
    unsigned short* AF = S2 + 42467328;                 // 42,467,328 bf16 (84.9 MB)
    unsigned short* WF = AF + 42467328;                 // 589,824 bf16 (1.2 MB)

    k_pinit<<<432, 64, 0, stream>>>(centers, spreads, p1, p2, p1t, p2t);
    k_gemmA<<<9216, 128, 0, stream>>>(hs, p1t, S2);
    k_gemmB<<<9216, 128, 0, stream>>>(S2, p2t, (unsigned int*)AF);
    k_wpack<<<288, 256, 0, stream>>>(Wv, WF);
    k_gemmC<<<576, 256, 0, stream>>>(AF, WF, vbias, out);
    k_probs<<<20736, 256, 0, stream>>>(p1, p2, probs);
}

// Round 3
// 326.720 us; speedup vs baseline: 2.7937x; 1.5888x over previous
//
#include <hip/hip_runtime.h>
#include <cstdint>
#include <cstddef>

// Problem constants
#define NHEAD 9
#define CHN   256
#define NB    8
#define WH    48
#define SS    2304            // 48*48
#define OUT0  4718592         // 8*256*48*48
// probs region: 47,775,744 floats after OUT0

typedef short bf16x8 __attribute__((ext_vector_type(8)));
typedef float f32x4  __attribute__((ext_vector_type(4)));

__device__ __forceinline__ float bf2f(unsigned int u16) {
    union { unsigned int i; float f; } v; v.i = u16 << 16; return v.f;
}
__device__ __forceinline__ unsigned short f2bf(float f) {
    union { float f; unsigned int i; } v; v.f = f;
    unsigned int x = v.i;
    unsigned int r = x + 0x7fffu + ((x >> 16) & 1u);   // RNE
    return (unsigned short)(r >> 16);
}

// ---------------------------------------------------------------------------
// K1: 1D softmaxes. fp32 p1/p2 (for k_probs) + bf16 zero-padded-to-64 p1b/p2b
// (MFMA operand staging for k_attn).  grid: 432 blocks (h*48+r), 64 threads
// ---------------------------------------------------------------------------
__global__ __launch_bounds__(64) void k_pinit(const float* __restrict__ centers,
                                              const float* __restrict__ spreads,
                                              float* __restrict__ p1, float* __restrict__ p2,
                                              unsigned short* __restrict__ p1b,
                                              unsigned short* __restrict__ p2b) {
    int blk = blockIdx.x;
    int h = blk / 48, r = blk % 48;
    int lane = threadIdx.x;
    float a = spreads[h]; a = a * a;
    float mu1 = centers[2 * h + 0];
    float mu2 = centers[2 * h + 1];
    bool act = lane < 48;
    float dx = (float)(lane - r);
    float q  = -0.5f * a * dx * dx;
    float g1 = act ? (a * mu1 * dx + q) : -INFINITY;
    float g2 = act ? (a * mu2 * dx + q) : -INFINITY;
    float m1 = g1, m2 = g2;
    #pragma unroll
    for (int off = 32; off >= 1; off >>= 1) {
        m1 = fmaxf(m1, __shfl_xor(m1, off));
        m2 = fmaxf(m2, __shfl_xor(m2, off));
    }
    float e1 = act ? expf(g1 - m1) : 0.f;
    float e2 = act ? expf(g2 - m2) : 0.f;
    float s1 = e1, s2 = e2;
    #pragma unroll
    for (int off = 32; off >= 1; off >>= 1) {
        s1 += __shfl_xor(s1, off);
        s2 += __shfl_xor(s2, off);
    }
    float v1 = e1 / s1, v2 = e2 / s2;
    if (act) {
        p1[h * SS + r * 48 + lane] = v1;
        p2[h * SS + r * 48 + lane] = v2;
    }
    // bf16, K-padded to 64 with zeros (rows = 128 B)
    p1b[(h * 48 + r) * 64 + lane] = act ? f2bf(v1) : 0;
    p2b[(h * 48 + r) * 64 + lane] = act ? f2bf(v2) : 0;
}

// ---------------------------------------------------------------------------
// K2: hs fp32 [bd][l][48] -> hsb bf16 [bd][l][64] (zero-padded rows, 128 B)
// grid 2048 x 256
// ---------------------------------------------------------------------------
__global__ __launch_bounds__(256) void k_hpack(const float* __restrict__ hs,
                                               unsigned short* __restrict__ hsb) {
    int bd = blockIdx.x;
    int t = threadIdx.x;
    const float* src = hs + (size_t)bd * SS;
    unsigned short* dst = hsb + (size_t)bd * 3072;
    for (int u = t; u < 384; u += 256) {
        int l = u >> 3, c8 = u & 7;
        uint4 o = {0u, 0u, 0u, 0u};
        if (c8 < 6) {
            const float* p = src + l * 48 + c8 * 8;
            float4 f0 = *(const float4*)p;
            float4 f1 = *(const float4*)(p + 4);
            o.x = (unsigned int)f2bf(f0.x) | ((unsigned int)f2bf(f0.y) << 16);
            o.y = (unsigned int)f2bf(f0.z) | ((unsigned int)f2bf(f0.w) << 16);
            o.z = (unsigned int)f2bf(f1.x) | ((unsigned int)f2bf(f1.y) << 16);
            o.w = (unsigned int)f2bf(f1.z) | ((unsigned int)f2bf(f1.w) << 16);
        }
        *(uint4*)(dst + l * 64 + c8 * 8) = o;
    }
}

// ---------------------------------------------------------------------------
// K3 (fused attention apply, MFMA):
//   per (h, bd):  S[i,l] = sum_k p1[h,i,k] * X_bd[l,k]      (mfma1)
//                 V^T[i,j] = sum_l S[i,l]  * p2[h,j,l]      (mfma2)
//   vals element (k=h*256+d, m=j*48+i) -> AF[b][kb][m][kk]  (gemmC A-frag layout)
// Block: 256 thr = 4 waves, one (h, b, d-octet).  Wave: 2 d's sequentially.
// S transpose via wave-private LDS; AF kk-transpose via block Vbuf LDS.
// grid: 2304 = h*256 + b*32 + od
// ---------------------------------------------------------------------------
__global__ __launch_bounds__(256, 2) void k_attn(const unsigned short* __restrict__ hsb,
                                                 const unsigned short* __restrict__ p1b,
                                                 const unsigned short* __restrict__ p2b,
                                                 unsigned short* __restrict__ AF) {
    __shared__ unsigned short Sbuf[4 * 3456];   // per-wave: 48 rows x 72 (pitch) bf16
    __shared__ unsigned short Vbuf[8 * 2304];   // [kk][m]

    int blk = blockIdx.x;
    int h = blk >> 8;
    int rem = blk & 255;
    int b = rem >> 5, od = rem & 31;
    int d0 = od * 8;
    int kb = h * 32 + od;

    int t = threadIdx.x;
    int lane = t & 63, wave = t >> 6;
    int l15 = lane & 15, quad = lane >> 4;

    // Preload p1 A-frags and p2 B-frags: [tile][kt], lane = row tile*16+l15, 16B at kt*32+quad*8
    const bf16x8* P1 = (const bf16x8*)(p1b + (size_t)h * 3072);
    const bf16x8* P2 = (const bf16x8*)(p2b + (size_t)h * 3072);
    bf16x8 pa[3][2], pb[3][2];
    #pragma unroll
    for (int tt = 0; tt < 3; ++tt)
        #pragma unroll
        for (int kt = 0; kt < 2; ++kt) {
            int u = (tt * 16 + l15) * 8 + kt * 4 + quad;
            pa[tt][kt] = P1[u];
            pb[tt][kt] = P2[u];
        }

    // Zero S pad columns 48..63 (wave-private, persists across the 2 d's)
    unsigned short* Sw = Sbuf + wave * 3456;
    for (int z = lane; z < 384; z += 64) {
        int row = z >> 3;
        *(unsigned int*)(Sw + row * 72 + 48 + ((z & 7) << 1)) = 0u;
    }

    for (int s = 0; s < 2; ++s) {
        int d = d0 + wave * 2 + s;
        int kk = wave * 2 + s;
        size_t bd = (size_t)b * 256 + d;
        const bf16x8* X = (const bf16x8*)(hsb + bd * 3072);

        // B1-frags: lane holds X[l = lt*16+l15][kt*32+quad*8 ..+7]
        bf16x8 bx[3][2];
        #pragma unroll
        for (int lt = 0; lt < 3; ++lt)
            #pragma unroll
            for (int kt = 0; kt < 2; ++kt)
                bx[lt][kt] = X[(lt * 16 + l15) * 8 + kt * 4 + quad];

        // mfma1: S[i,l]
        f32x4 a1[9];
        #pragma unroll
        for (int q = 0; q < 9; ++q) a1[q] = (f32x4){0.f, 0.f, 0.f, 0.f};
        #pragma unroll
        for (int it = 0; it < 3; ++it)
            #pragma unroll
            for (int lt = 0; lt < 3; ++lt) {
                a1[it * 3 + lt] = __builtin_amdgcn_mfma_f32_16x16x32_bf16(
                    pa[it][0], bx[lt][0], a1[it * 3 + lt], 0, 0, 0);
                a1[it * 3 + lt] = __builtin_amdgcn_mfma_f32_16x16x32_bf16(
                    pa[it][1], bx[lt][1], a1[it * 3 + lt], 0, 0, 0);
            }

        // S -> LDS (bf16), D-layout: row i = it*16+quad*4+r, col l = lt*16+l15
        #pragma unroll
        for (int it = 0; it < 3; ++it)
            #pragma unroll
            for (int lt = 0; lt < 3; ++lt)
                #pragma unroll
                for (int r = 0; r < 4; ++r)
                    Sw[(it * 16 + quad * 4 + r) * 72 + lt * 16 + l15] =
                        f2bf(a1[it * 3 + lt][r]);

        // A2-frags from S: lane holds S[i = it*16+l15][kt*32+quad*8 ..+7]
        bf16x8 a2f[3][2];
        #pragma unroll
        for (int it = 0; it < 3; ++it)
            #pragma unroll
            for (int kt = 0; kt < 2; ++kt)
                a2f[it][kt] = *(const bf16x8*)(Sw + (it * 16 + l15) * 72 + kt * 32 + quad * 8);

        // mfma2: V^T[i,j]
        f32x4 a2[9];
        #pragma unroll
        for (int q = 0; q < 9; ++q) a2[q] = (f32x4){0.f, 0.f, 0.f, 0.f};
        #pragma unroll
        for (int it = 0; it < 3; ++it)
            #pragma unroll
            for (int jt = 0; jt < 3; ++jt) {
                a2[it * 3 + jt] = __builtin_amdgcn_mfma_f32_16x16x32_bf16(
                    a2f[it][0], pb[jt][0], a2[it * 3 + jt], 0, 0, 0);
                a2[it * 3 + jt] = __builtin_amdgcn_mfma_f32_16x16x32_bf16(
                    a2f[it][1], pb[jt][1], a2[it * 3 + jt], 0, 0, 0);
            }

        // Vbuf[kk][m]: lane holds i = it*16+quad*4+(0..3) consecutive -> m consecutive
        #pragma unroll
        for (int it = 0; it < 3; ++it)
            #pragma unroll
            for (int jt = 0; jt < 3; ++jt) {
                f32x4 v = a2[it * 3 + jt];
                unsigned int lo = (unsigned int)f2bf(v[0]) | ((unsigned int)f2bf(v[1]) << 16);
                unsigned int hi = (unsigned int)f2bf(v[2]) | ((unsigned int)f2bf(v[3]) << 16);
                int m = (jt * 16 + l15) * 48 + it * 16 + quad * 4;
                uint2 u2; u2.x = lo; u2.y = hi;
                *(uint2*)(Vbuf + kk * 2304 + m) = u2;
            }
    }

    __syncthreads();

    // Output: AF[b][kb][m][kk] <- Vbuf[kk][m], 4 m per group, perm-transpose
    const uint2* Vr = (const uint2*)Vbuf;     // 576 uint2 per kk row
    uint4* AFq = (uint4*)AF;
    size_t abase = (size_t)(b * 288 + kb) * 2304;
    for (int g = t; g < 576; g += 256) {
        uint2 rk[8];
        #pragma unroll
        for (int kk = 0; kk < 8; ++kk) rk[kk] = Vr[kk * 576 + g];
        #pragma unroll
        for (int mi = 0; mi < 4; ++mi) {
            unsigned int sel = (mi & 1) ? 0x07060302u : 0x05040100u;
            uint4 o;
            if (mi < 2) {
                o.x = __builtin_amdgcn_perm(rk[1].x, rk[0].x, sel);
                o.y = __builtin_amdgcn_perm(rk[3].x, rk[2].x, sel);
                o.z = __builtin_amdgcn_perm(rk[5].x, rk[4].x, sel);
                o.w = __builtin_amdgcn_perm(rk[7].x, rk[6].x, sel);
            } else {
                o.x = __builtin_amdgcn_perm(rk[1].y, rk[0].y, sel);
                o.y = __builtin_amdgcn_perm(rk[3].y, rk[2].y, sel);
                o.z = __builtin_amdgcn_perm(rk[5].y, rk[4].y, sel);
                o.w = __builtin_amdgcn_perm(rk[7].y, rk[6].y, sel);
            }
            AFq[abase + g * 4 + mi] = o;
        }
    }
}

// ---------------------------------------------------------------------------
// K4: pack Wv (fp32 [e][k]) -> WF bf16 [kb][e][kk]  (MFMA B-fragment-ready)
// ---------------------------------------------------------------------------
__global__ __launch_bounds__(256) void k_wpack(const float* __restrict__ Wv,
                                               unsigned short* __restrict__ WF) {
    int kb = blockIdx.x;       // 0..287
    int e  = threadIdx.x;      // 0..255
    const float* src = Wv + (size_t)e * 2304 + kb * 8;
    float4 f0 = *(const float4*)src;
    float4 f1 = *(const float4*)(src + 4);
    uint4 o;
    o.x = (unsigned int)f2bf(f0.x) | ((unsigned int)f2bf(f0.y) << 16);
    o.y = (unsigned int)f2bf(f0.z) | ((unsigned int)f2bf(f0.w) << 16);
    o.z = (unsigned int)f2bf(f1.x) | ((unsigned int)f2bf(f1.y) << 16);
    o.w = (unsigned int)f2bf(f1.z) | ((unsigned int)f2bf(f1.w) << 16);
    *(uint4*)(WF + ((size_t)kb * 256 + e) * 8) = o;
}

// ---------------------------------------------------------------------------
// K5 (GEMM-C, MFMA): out[b][e][m] = sum_k AF(k,m)*W(e,k) + vb[e]
// grid: 576 = b*72 + mb*2 + nbk, 256 thr, no LDS, no barriers
// ---------------------------------------------------------------------------
__global__ __launch_bounds__(256) void k_gemmC(const unsigned short* __restrict__ AF,
                                               const unsigned short* __restrict__ WF,
                                               const float* __restrict__ vb,
                                               float* __restrict__ out) {
    int blk = blockIdx.x;
    int b = blk / 72; int r = blk % 72; int mb = r >> 1; int nbk = r & 1;
    int t = threadIdx.x;
    int lane = t & 63, wave = t >> 6;
    int l15 = lane & 15, quad = lane >> 4;
    int wm = wave & 1, we = wave >> 1;
    int m0 = mb * 64 + wm * 32;
    int e0 = nbk * 128 + we * 64;

    const bf16x8* pa = (const bf16x8*)AF + (size_t)b * 288 * 2304
                       + (size_t)quad * 2304 + m0 + l15;
    const bf16x8* pw = (const bf16x8*)WF + (size_t)quad * 256 + e0 + l15;

    f32x4 acc[2][4];
    #pragma unroll
    for (int i = 0; i < 2; i++)
        #pragma unroll
        for (int j = 0; j < 4; j++) acc[i][j] = (f32x4){0.f, 0.f, 0.f, 0.f};

    bf16x8 a_cur[2], w_cur[4], a_nxt[2], w_nxt[4];
    a_cur[0] = pa[0];  a_cur[1] = pa[16];
    w_cur[0] = pw[0];  w_cur[1] = pw[16]; w_cur[2] = pw[32]; w_cur[3] = pw[48];

    for (int c = 0; c < 72; ++c) {
        if (c < 71) {
            a_nxt[0] = pa[9216];      a_nxt[1] = pa[9216 + 16];
            w_nxt[0] = pw[1024];      w_nxt[1] = pw[1024 + 16];
            w_nxt[2] = pw[1024 + 32]; w_nxt[3] = pw[1024 + 48];
        }
        #pragma unroll
        for (int tm = 0; tm < 2; ++tm)
            #pragma unroll
            for (int te = 0; te < 4; ++te)
                acc[tm][te] = __builtin_amdgcn_mfma_f32_16x16x32_bf16(
                    a_cur[tm], w_cur[te], acc[tm][te], 0, 0, 0);
        a_cur[0] = a_nxt[0]; a_cur[1] = a_nxt[1];
        w_cur[0] = w_nxt[0]; w_cur[1] = w_nxt[1]; w_cur[2] = w_nxt[2]; w_cur[3] = w_nxt[3];
        pa += 9216; pw += 1024;
    }

    size_t obase = (size_t)b * 589824;
    #pragma unroll
    for (int te = 0; te < 4; ++te) {
        int e = e0 + te * 16 + l15;
        float bias = vb[e];
        #pragma unroll
        for (int tm = 0; tm < 2; ++tm) {
            int m = m0 + tm * 16 + quad * 4;
            float4 v;
            v.x = acc[tm][te][0] + bias;
            v.y = acc[tm][te][1] + bias;
            v.z = acc[tm][te][2] + bias;
            v.w = acc[tm][te][3] + bias;
            *(float4*)(out + obase + (size_t)e * 2304 + m) = v;
        }
    }
}

// ---------------------------------------------------------------------------
// K6: probs output (runs last, overwrites scratch region)
// ---------------------------------------------------------------------------
__global__ __launch_bounds__(256) void k_probs(const float* __restrict__ p1,
                                               const float* __restrict__ p2,
                                               float* __restrict__ probs) {
    int blk = blockIdx.x;
    int h = blk % 9; int ij = blk / 9; int j = ij % 48; int i = ij / 48;
    __shared__ float p1row[48];
    __shared__ float4 p2row[12];
    int t = threadIdx.x;
    if (t < 48) p1row[t] = p1[(h * 48 + i) * 48 + t];
    else if (t < 60) p2row[t - 48] = ((const float4*)(p2 + (h * 48 + j) * 48))[t - 48];
    __syncthreads();
    float4* op = (float4*)(probs + (size_t)blk * SS);
    for (int idx = t; idx < 576; idx += 256) {
        int e4 = idx * 4;
        int k = e4 / 48, l = e4 % 48;
        float s = p1row[k];
        float4 qv = p2row[l >> 2];
        float4 v; v.x = s * qv.x; v.y = s * qv.y; v.z = s * qv.z; v.w = s * qv.w;
        op[idx] = v;
    }
}

// ---------------------------------------------------------------------------
extern "C" void kernel_launch(void* const* d_in, const int* in_sizes, int n_in,
                              void* d_out, int out_size, void* d_ws, size_t ws_size,
                              hipStream_t stream) {
    const float* hs      = (const float*)d_in[0];
    const float* centers = (const float*)d_in[1];
    const float* spreads = (const float*)d_in[2];
    const float* Wv      = (const float*)d_in[3];
    const float* vbias   = (const float*)d_in[4];

    float* out   = (float*)d_out;
    float* probs = out + OUT0;                   // 47,775,744 floats (191 MB)

    float* p1  = (float*)d_ws;                   // 20736 floats each
    float* p2  = p1 + 20736;
    unsigned short* p1b = (unsigned short*)(p2 + 20736);  // 27648 bf16 each
    unsigned short* p2b = p1b + 27648;

    // Big scratch in the probs output region; k_probs runs last and overwrites.
    unsigned short* AF  = (unsigned short*)probs;   // 42,467,328 bf16 (84.9 MB)
    unsigned short* WF  = AF + 42467328;            // 589,824 bf16 (1.2 MB)
    unsigned short* hsb = WF + 589824;              // 6,291,456 bf16 (12.6 MB)

    k_pinit<<<432, 64, 0, stream>>>(centers, spreads, p1, p2, p1b, p2b);
    k_hpack<<<2048, 256, 0, stream>>>(hs, hsb);
    k_wpack<<<288, 256, 0, stream>>>(Wv, WF);
    k_attn<<<2304, 256, 0, stream>>>(hsb, p1b, p2b, AF);
    k_gemmC<<<576, 256, 0, stream>>>(AF, WF, vbias, out);
    k_probs<<<20736, 256, 0, stream>>>(p1, p2, probs);
}